// Round 6
// baseline (53.460 us; speedup 1.0000x reference)
//
#include <hip/hip_runtime.h>

static constexpr float ALPHA = 0.1f;

#define TW 64
#define TH 8
// hist window: rows h0-4 .. h0+11 (16 rows), data cols w0-8 .. w0+75 (84 cols)
// jitter: |dx| < 4.8 px, |dy| < 2.7 px -> taps within [w-6,w+6] x [h-4,h+4]
#define HROWS 16
#define HCOLS 84           // valid data columns
#define HSTRIDE 98         // row stride: 98 ≡ 2 (mod 32 banks) -> tap-row spread
                           // shifts banks by only 2/row => near-permutation
#define CHOFF (HROWS * HSTRIDE)   // 1568 words; channel byte offset 6272

__device__ __forceinline__ int iclamp(int v, int lo, int hi) { return min(max(v, lo), hi); }

struct Setup {
    int mA, m1, mB;       // global tap coords (unclamped); m2 = m1 + 1
    float t, w0, w3, w12;
};

__device__ __forceinline__ Setup axis_setup(float gcoord, float S) {
    Setup s;
    float pos = (gcoord + 1.0f) * 0.5f * S;
    float pm  = floorf(pos - 0.5f);
    float f   = pos - (pm + 0.5f);
    float f2 = f * f, f3 = f2 * f;
    s.w0  = -0.5f * f3 + f2 - 0.5f * f;
    float w2 = -1.5f * f3 + 2.0f * f2 + 0.5f * f;
    s.w3  =  0.5f * f3 - 0.5f * f2;
    s.w12 = (1.5f * f3 - 2.5f * f2 + 1.0f) + w2;
    float p12 = pm + __fdividef(w2, s.w12);
    float fl  = floorf(p12);
    s.t = p12 - fl;
    int m = (int)pm;
    s.m1 = (int)fl;
    s.mA = m - 1; s.mB = m + 2;
    return s;
}

__global__ __launch_bounds__(256, 4) void taa_kernel(
    const float* __restrict__ x, const float* __restrict__ mv,
    const float* __restrict__ hist, float* __restrict__ out)
{
    constexpr int N = 2, H = 1080, W = 1920, HW = H * W;
    constexpr int NTX = W / TW;          // 30
    constexpr int NTY = H / TH;          // 135
    constexpr int NWG = N * NTX * NTY;   // 8100
    constexpr int Q = NWG / 8, R = NWG % 8;

    __shared__ __align__(16) float Lh[3 * CHOFF];

    // Bijective XCD swizzle: each XCD owns a contiguous band of x-major work
    // ids -> vertically adjacent tiles share an XCD's L2 (FETCH 231->65 MB).
    int d = blockIdx.x;
    int xcd = d & 7, di = d >> 3;
    int work = (xcd < R ? xcd * (Q + 1) : R * (Q + 1) + (xcd - R) * Q) + di;
    int n   = work / (NTX * NTY);
    int rem = work - n * (NTX * NTY);
    int ty  = rem / NTX;
    int tx  = rem - ty * NTX;
    const int w0 = tx * TW, h0 = ty * TH;

    const int lx = threadIdx.x & 63;
    const int wv = threadIdx.x >> 6;      // 0..3; thread owns rows 2wv, 2wv+1
    const int wpix = w0 + lx;
    const int hbase = h0 + 2 * wv;

    const float* hn = hist + n * 3 * HW;
    const float* xn = x    + n * 3 * HW;

    // ---- mv loads (coalesced float2, issue first) ----
    const float2 g0 = ((const float2*)mv)[n * HW + hbase * W + wpix];
    const float2 g1 = ((const float2*)mv)[n * HW + (hbase + 1) * W + wpix];

    // Interior: staging needs no image clamp AND taps never clamp at image
    // border AND window-local indices never clamp.
    const bool interior = (tx >= 1) && (tx <= NTX - 2) && (ty >= 1) && (ty <= NTY - 2);

    // ---- stage history window into LDS ----
    if (interior) {
        for (int idx = threadIdx.x; idx < 1008; idx += 256) {     // 3*16*21 float4
            int c  = idx / 336;
            int rm = idx - c * 336;
            int r  = rm / 21;
            int c4 = rm - r * 21;
            const float4 v = *(const float4*)(hn + c * HW + (h0 - 4 + r) * W + (w0 - 8) + c4 * 4);
            float* dst = Lh + c * CHOFF + r * HSTRIDE + c4 * 4;   // 8B-aligned
            dst[0] = v.x; dst[1] = v.y; dst[2] = v.z; dst[3] = v.w;
        }
    } else {
        for (int idx = threadIdx.x; idx < 4032; idx += 256) {     // 3*16*84 scalar
            int c  = idx / 1344;
            int rm = idx - c * 1344;
            int r  = rm / HCOLS;
            int cc = rm - r * HCOLS;
            int gr = iclamp(h0 - 4 + r, 0, H - 1);
            int gc = iclamp(w0 - 8 + cc, 0, W - 1);
            Lh[c * CHOFF + r * HSTRIDE + cc] = hn[c * HW + gr * W + gc];
        }
    }

    // ---- x neighborhood (coalesced VMEM; overlaps staging latency) ----
    int rg0 = iclamp(hbase - 1, 0, H - 1) * W;
    int rg1 = hbase * W;
    int rg2 = (hbase + 1) * W;
    int rg3 = iclamp(hbase + 2, 0, H - 1) * W;
    const int rg[4] = {rg0, rg1, rg2, rg3};

    float hmx[3][4], hmn[3][4], xmid[3][4];
    if (tx >= 1 && tx <= NTX - 2) {
#pragma unroll
        for (int c = 0; c < 3; ++c) {
            const float* xc = xn + c * HW + wpix;
#pragma unroll
            for (int rr = 0; rr < 4; ++rr) {
                const float* p = xc + rg[rr];
                float a = p[-1], b = p[0], e = p[1];
                hmx[c][rr]  = fmaxf(fmaxf(a, b), e);
                hmn[c][rr]  = fminf(fminf(a, b), e);
                xmid[c][rr] = b;
            }
        }
    } else {
        const int wm = max(wpix - 1, 0), wp = min(wpix + 1, W - 1);
#pragma unroll
        for (int c = 0; c < 3; ++c) {
            const float* xc = xn + c * HW;
#pragma unroll
            for (int rr = 0; rr < 4; ++rr) {
                float a = xc[rg[rr] + wm];
                float b = xc[rg[rr] + wpix];
                float e = xc[rg[rr] + wp];
                hmx[c][rr]  = fmaxf(fmaxf(a, b), e);
                hmn[c][rr]  = fminf(fminf(a, b), e);
                xmid[c][rr] = b;
            }
        }
    }

    // ---- bicubic setup for both pixels (overlaps staging latency) ----
    Setup sx0 = axis_setup(g0.x, (float)W);
    Setup sy0 = axis_setup(g0.y, (float)H);
    Setup sx1 = axis_setup(g1.x, (float)W);
    Setup sy1 = axis_setup(g1.y, (float)H);

    __syncthreads();

    float* on = out + n * 3 * HW;

#pragma unroll
    for (int p = 0; p < 2; ++p) {
        const Setup& sx = p ? sx1 : sx0;
        const Setup& sy = p ? sy1 : sy0;

        const float tx_ = sx.t, ty_ = sy.t;
        const float omtx = 1.0f - tx_, omty = 1.0f - ty_;
        const float ww1 = sx.w12 * sy.w0;
        const float ww2 = sx.w0  * sy.w12;
        const float ww3 = sx.w3  * sy.w12;
        const float ww4 = sx.w12 * sy.w3;
        const float ww5 = sx.w12 * sy.w12;
        const float rrec = __fdividef(1.0f, ww1 + ww2 + ww3 + ww4 + ww5);

        float reproj[3];

        if (interior) {
            // no clamps: lr2 = lr1+1, lc2 = lc1+1 guaranteed; same-base pairs
            // merge into ds_read2_b32 (offset1: +1 horizontal, +98 vertical)
            const int rA = (sy.mA - (h0 - 4)) * HSTRIDE;
            const int r1 = (sy.m1 - (h0 - 4)) * HSTRIDE;
            const int rB = (sy.mB - (h0 - 4)) * HSTRIDE;
            const int lcA = sx.mA - (w0 - 8);
            const int lc1 = sx.m1 - (w0 - 8);
            const int lcB = sx.mB - (w0 - 8);
#pragma unroll
            for (int c = 0; c < 3; ++c) {
                const float* Lc = Lh + c * CHOFF;
                const float* pA = Lc + rA + lc1;
                const float* pB = Lc + rB + lc1;
                const float* pL = Lc + r1 + lcA;
                const float* pR = Lc + r1 + lcB;
                const float* pC = Lc + r1 + lc1;
                float a0 = pA[0], a1 = pA[1];
                float b0 = pB[0], b1 = pB[1];
                float l0 = pL[0], l1 = pL[HSTRIDE];
                float q0 = pR[0], q1 = pR[HSTRIDE];
                float c00 = pC[0], c01 = pC[1];
                float c10 = pC[HSTRIDE], c11 = pC[HSTRIDE + 1];
                float s1 = a0 * omtx + a1 * tx_;
                float s4 = b0 * omtx + b1 * tx_;
                float s2 = l0 * omty + l1 * ty_;
                float s3 = q0 * omty + q1 * ty_;
                float s5 = (c00 * omtx + c01 * tx_) * omty + (c10 * omtx + c11 * tx_) * ty_;
                reproj[c] = (s1 * ww1 + s2 * ww2 + s3 * ww3 + s4 * ww4 + s5 * ww5) * rrec;
            }
        } else {
            const int lrA = iclamp(sy.mA     - (h0 - 4), 0, HROWS - 1);
            const int lr1 = iclamp(sy.m1     - (h0 - 4), 0, HROWS - 1);
            const int lr2 = iclamp(sy.m1 + 1 - (h0 - 4), 0, HROWS - 1);
            const int lrB = iclamp(sy.mB     - (h0 - 4), 0, HROWS - 1);
            const int lcA = iclamp(sx.mA     - (w0 - 8), 0, HCOLS - 1);
            const int lc1 = iclamp(sx.m1     - (w0 - 8), 0, HCOLS - 1);
            const int lc2 = iclamp(sx.m1 + 1 - (w0 - 8), 0, HCOLS - 1);
            const int lcB = iclamp(sx.mB     - (w0 - 8), 0, HCOLS - 1);
            const int rA = lrA * HSTRIDE, r1 = lr1 * HSTRIDE, r2 = lr2 * HSTRIDE, rB = lrB * HSTRIDE;
#pragma unroll
            for (int c = 0; c < 3; ++c) {
                const float* L = Lh + c * CHOFF;
                float s1   = L[rA + lc1] * omtx + L[rA + lc2] * tx_;
                float s4   = L[rB + lc1] * omtx + L[rB + lc2] * tx_;
                float s2   = L[r1 + lcA] * omty + L[r2 + lcA] * ty_;
                float s3   = L[r1 + lcB] * omty + L[r2 + lcB] * ty_;
                float top5 = L[r1 + lc1] * omtx + L[r1 + lc2] * tx_;
                float bot5 = L[r2 + lc1] * omtx + L[r2 + lc2] * tx_;
                float s5   = top5 * omty + bot5 * ty_;
                reproj[c] = (s1 * ww1 + s2 * ww2 + s3 * ww3 + s4 * ww4 + s5 * ww5) * rrec;
            }
        }

        const int gpix = (hbase + p) * W + wpix;
#pragma unroll
        for (int c = 0; c < 3; ++c) {
            float mxv = fmaxf(fmaxf(hmx[c][p], hmx[c][p + 1]), hmx[c][p + 2]);
            float mnv = fminf(fminf(hmn[c][p], hmn[c][p + 1]), hmn[c][p + 2]);
            float rp = fminf(fmaxf(reproj[c], mnv), mxv);
            on[c * HW + gpix] = ALPHA * xmid[c][p + 1] + (1.0f - ALPHA) * rp;
        }
    }
}

extern "C" void kernel_launch(void* const* d_in, const int* in_sizes, int n_in,
                              void* d_out, int out_size, void* d_ws, size_t ws_size,
                              hipStream_t stream) {
    const float* x    = (const float*)d_in[0];
    const float* mv   = (const float*)d_in[1];
    const float* hist = (const float*)d_in[2];
    float* out = (float*)d_out;

    constexpr int NWG = 2 * (1920 / TW) * (1080 / TH);  // 8100
    taa_kernel<<<dim3(NWG, 1, 1), dim3(256, 1, 1), 0, stream>>>(x, mv, hist, out);
}

// Round 7
// 53.012 us; speedup vs baseline: 1.0084x; 1.0084x over previous
//
#include <hip/hip_runtime.h>

static constexpr float ALPHA = 0.1f;

#define TW 64
#define TH 8
// hist window: rows h0-4 .. h0+11 (16 rows), data cols w0-8 .. w0+75 (84 cols)
// jitter: |dx| < 4.8 px, |dy| < 2.7 px -> taps within [w-6,w+6] x [h-4,h+4]
#define HROWS 16
#define HCOLS 84           // valid data columns
#define HSTRIDE 96         // ≡ 0 (mod 32 banks): banking is ROW-INVARIANT ->
                           // per-lane bank = lane + δx only (δx ∈ ±6), row
                           // jitter cannot collide lanes. 96*4 ≡ 0 mod 16 ->
                           // b128 staging writes stay aligned.
#define CHOFF (HROWS * HSTRIDE)   // 1536 words; channel byte offset 6144

__device__ __forceinline__ int iclamp(int v, int lo, int hi) { return min(max(v, lo), hi); }

struct Setup {
    int mA, m1, mB;       // global tap coords (unclamped); m2 = m1 + 1
    float t, w0, w3, w12;
};

__device__ __forceinline__ Setup axis_setup(float gcoord, float S) {
    Setup s;
    float pos = (gcoord + 1.0f) * 0.5f * S;
    float pm  = floorf(pos - 0.5f);
    float f   = pos - (pm + 0.5f);
    float f2 = f * f, f3 = f2 * f;
    s.w0  = -0.5f * f3 + f2 - 0.5f * f;
    float w2 = -1.5f * f3 + 2.0f * f2 + 0.5f * f;
    s.w3  =  0.5f * f3 - 0.5f * f2;
    s.w12 = (1.5f * f3 - 2.5f * f2 + 1.0f) + w2;
    float p12 = pm + __fdividef(w2, s.w12);
    float fl  = floorf(p12);
    s.t = p12 - fl;
    int m = (int)pm;
    s.m1 = (int)fl;
    s.mA = m - 1; s.mB = m + 2;
    return s;
}

__global__ __launch_bounds__(256, 4) void taa_kernel(
    const float* __restrict__ x, const float* __restrict__ mv,
    const float* __restrict__ hist, float* __restrict__ out)
{
    constexpr int N = 2, H = 1080, W = 1920, HW = H * W;
    constexpr int NTX = W / TW;          // 30
    constexpr int NTY = H / TH;          // 135
    constexpr int NWG = N * NTX * NTY;   // 8100
    constexpr int Q = NWG / 8, R = NWG % 8;

    __shared__ __align__(16) float Lh[3 * CHOFF];

    // Bijective XCD swizzle: each XCD owns a contiguous band of x-major work
    // ids -> vertically adjacent tiles share an XCD's L2 (FETCH 231->65 MB).
    int d = blockIdx.x;
    int xcd = d & 7, di = d >> 3;
    int work = (xcd < R ? xcd * (Q + 1) : R * (Q + 1) + (xcd - R) * Q) + di;
    int n   = work / (NTX * NTY);
    int rem = work - n * (NTX * NTY);
    int ty  = rem / NTX;
    int tx  = rem - ty * NTX;
    const int w0 = tx * TW, h0 = ty * TH;

    const int lx = threadIdx.x & 63;
    const int wv = threadIdx.x >> 6;      // 0..3; thread owns rows 2wv, 2wv+1
    const int wpix = w0 + lx;
    const int hbase = h0 + 2 * wv;

    const float* hn = hist + n * 3 * HW;
    const float* xn = x    + n * 3 * HW;

    // ---- mv loads (coalesced float2, issue first) ----
    const float2 g0 = ((const float2*)mv)[n * HW + hbase * W + wpix];
    const float2 g1 = ((const float2*)mv)[n * HW + (hbase + 1) * W + wpix];

    const bool interior = (tx >= 1) && (tx <= NTX - 2) && (ty >= 1) && (ty <= NTY - 2);

    // ---- stage history window into LDS ----
    if (interior) {
        float4* Lh4 = (float4*)Lh;
        for (int idx = threadIdx.x; idx < 1008; idx += 256) {     // 3*16*21 float4
            int c  = idx / 336;
            int rm = idx - c * 336;
            int r  = rm / 21;
            int c4 = rm - r * 21;
            // dst float4 index: c*384 + r*24 + c4 (row stride 24 float4 = 96 words)
            Lh4[c * 384 + r * 24 + c4] =
                *(const float4*)(hn + c * HW + (h0 - 4 + r) * W + (w0 - 8) + c4 * 4);
        }
    } else {
        for (int idx = threadIdx.x; idx < 4032; idx += 256) {     // 3*16*84 scalar
            int c  = idx / 1344;
            int rm = idx - c * 1344;
            int r  = rm / HCOLS;
            int cc = rm - r * HCOLS;
            int gr = iclamp(h0 - 4 + r, 0, H - 1);
            int gc = iclamp(w0 - 8 + cc, 0, W - 1);
            Lh[c * CHOFF + r * HSTRIDE + cc] = hn[c * HW + gr * W + gc];
        }
    }

    // ---- x neighborhood (coalesced VMEM; overlaps staging latency) ----
    int rg0 = iclamp(hbase - 1, 0, H - 1) * W;
    int rg1 = hbase * W;
    int rg2 = (hbase + 1) * W;
    int rg3 = iclamp(hbase + 2, 0, H - 1) * W;
    const int rg[4] = {rg0, rg1, rg2, rg3};

    float hmx[3][4], hmn[3][4], xmid[3][4];
    if (tx >= 1 && tx <= NTX - 2) {
#pragma unroll
        for (int c = 0; c < 3; ++c) {
            const float* xc = xn + c * HW + wpix;
#pragma unroll
            for (int rr = 0; rr < 4; ++rr) {
                const float* p = xc + rg[rr];
                float a = p[-1], b = p[0], e = p[1];
                hmx[c][rr]  = fmaxf(fmaxf(a, b), e);
                hmn[c][rr]  = fminf(fminf(a, b), e);
                xmid[c][rr] = b;
            }
        }
    } else {
        const int wm = max(wpix - 1, 0), wp = min(wpix + 1, W - 1);
#pragma unroll
        for (int c = 0; c < 3; ++c) {
            const float* xc = xn + c * HW;
#pragma unroll
            for (int rr = 0; rr < 4; ++rr) {
                float a = xc[rg[rr] + wm];
                float b = xc[rg[rr] + wpix];
                float e = xc[rg[rr] + wp];
                hmx[c][rr]  = fmaxf(fmaxf(a, b), e);
                hmn[c][rr]  = fminf(fminf(a, b), e);
                xmid[c][rr] = b;
            }
        }
    }

    // ---- bicubic setup for both pixels (overlaps staging latency) ----
    Setup sx0 = axis_setup(g0.x, (float)W);
    Setup sy0 = axis_setup(g0.y, (float)H);
    Setup sx1 = axis_setup(g1.x, (float)W);
    Setup sy1 = axis_setup(g1.y, (float)H);

    __syncthreads();

    float* on = out + n * 3 * HW;

#pragma unroll
    for (int p = 0; p < 2; ++p) {
        const Setup& sx = p ? sx1 : sx0;
        const Setup& sy = p ? sy1 : sy0;

        const float tx_ = sx.t, ty_ = sy.t;
        const float omtx = 1.0f - tx_, omty = 1.0f - ty_;
        const float ww1 = sx.w12 * sy.w0;
        const float ww2 = sx.w0  * sy.w12;
        const float ww3 = sx.w3  * sy.w12;
        const float ww4 = sx.w12 * sy.w3;
        const float ww5 = sx.w12 * sy.w12;
        const float rrec = __fdividef(1.0f, ww1 + ww2 + ww3 + ww4 + ww5);

        float reproj[3];

        if (interior) {
            // no clamps needed (verified bounds: rows in [0,14], cols in [2,77]);
            // same-base pairs merge into ds_read2_b32 (offset1 = +1 / +96)
            const int rA = (sy.mA - (h0 - 4)) * HSTRIDE;
            const int r1 = (sy.m1 - (h0 - 4)) * HSTRIDE;
            const int rB = (sy.mB - (h0 - 4)) * HSTRIDE;
            const int lcA = sx.mA - (w0 - 8);
            const int lc1 = sx.m1 - (w0 - 8);
            const int lcB = sx.mB - (w0 - 8);
#pragma unroll
            for (int c = 0; c < 3; ++c) {
                const float* Lc = Lh + c * CHOFF;
                const float* pA = Lc + rA + lc1;
                const float* pB = Lc + rB + lc1;
                const float* pL = Lc + r1 + lcA;
                const float* pR = Lc + r1 + lcB;
                const float* pC = Lc + r1 + lc1;
                float a0 = pA[0], a1 = pA[1];
                float b0 = pB[0], b1 = pB[1];
                float l0 = pL[0], l1 = pL[HSTRIDE];
                float q0 = pR[0], q1 = pR[HSTRIDE];
                float c00 = pC[0], c01 = pC[1];
                float c10 = pC[HSTRIDE], c11 = pC[HSTRIDE + 1];
                float s1 = a0 * omtx + a1 * tx_;
                float s4 = b0 * omtx + b1 * tx_;
                float s2 = l0 * omty + l1 * ty_;
                float s3 = q0 * omty + q1 * ty_;
                float s5 = (c00 * omtx + c01 * tx_) * omty + (c10 * omtx + c11 * tx_) * ty_;
                reproj[c] = (s1 * ww1 + s2 * ww2 + s3 * ww3 + s4 * ww4 + s5 * ww5) * rrec;
            }
        } else {
            const int lrA = iclamp(sy.mA     - (h0 - 4), 0, HROWS - 1);
            const int lr1 = iclamp(sy.m1     - (h0 - 4), 0, HROWS - 1);
            const int lr2 = iclamp(sy.m1 + 1 - (h0 - 4), 0, HROWS - 1);
            const int lrB = iclamp(sy.mB     - (h0 - 4), 0, HROWS - 1);
            const int lcA = iclamp(sx.mA     - (w0 - 8), 0, HCOLS - 1);
            const int lc1 = iclamp(sx.m1     - (w0 - 8), 0, HCOLS - 1);
            const int lc2 = iclamp(sx.m1 + 1 - (w0 - 8), 0, HCOLS - 1);
            const int lcB = iclamp(sx.mB     - (w0 - 8), 0, HCOLS - 1);
            const int rA = lrA * HSTRIDE, r1 = lr1 * HSTRIDE, r2 = lr2 * HSTRIDE, rB = lrB * HSTRIDE;
#pragma unroll
            for (int c = 0; c < 3; ++c) {
                const float* L = Lh + c * CHOFF;
                float s1   = L[rA + lc1] * omtx + L[rA + lc2] * tx_;
                float s4   = L[rB + lc1] * omtx + L[rB + lc2] * tx_;
                float s2   = L[r1 + lcA] * omty + L[r2 + lcA] * ty_;
                float s3   = L[r1 + lcB] * omty + L[r2 + lcB] * ty_;
                float top5 = L[r1 + lc1] * omtx + L[r1 + lc2] * tx_;
                float bot5 = L[r2 + lc1] * omtx + L[r2 + lc2] * tx_;
                float s5   = top5 * omty + bot5 * ty_;
                reproj[c] = (s1 * ww1 + s2 * ww2 + s3 * ww3 + s4 * ww4 + s5 * ww5) * rrec;
            }
        }

        const int gpix = (hbase + p) * W + wpix;
#pragma unroll
        for (int c = 0; c < 3; ++c) {
            float mxv = fmaxf(fmaxf(hmx[c][p], hmx[c][p + 1]), hmx[c][p + 2]);
            float mnv = fminf(fminf(hmn[c][p], hmn[c][p + 1]), hmn[c][p + 2]);
            float rp = fminf(fmaxf(reproj[c], mnv), mxv);
            on[c * HW + gpix] = ALPHA * xmid[c][p + 1] + (1.0f - ALPHA) * rp;
        }
    }
}

extern "C" void kernel_launch(void* const* d_in, const int* in_sizes, int n_in,
                              void* d_out, int out_size, void* d_ws, size_t ws_size,
                              hipStream_t stream) {
    const float* x    = (const float*)d_in[0];
    const float* mv   = (const float*)d_in[1];
    const float* hist = (const float*)d_in[2];
    float* out = (float*)d_out;

    constexpr int NWG = 2 * (1920 / TW) * (1080 / TH);  // 8100
    taa_kernel<<<dim3(NWG, 1, 1), dim3(256, 1, 1), 0, stream>>>(x, mv, hist, out);
}